// Round 15
// baseline (4578.271 us; speedup 1.0000x reference)
//
#include <hip/hip_runtime.h>
#include <math.h>

#define T_DIM 256
#define B_DIM 64
#define KDIM 2048   // I*D == H*D
#define TBROWS 16384
#define NBLK 256      // persistent scan grid: 4 rq x 64 cs
#define HSLOT 262144  // ushorts per hx slot: 2 planes x 64 x 2048

constexpr float EPSF = 1e-15f;
constexpr float MAXN = 1.0f - 1e-5f;

typedef short bf16x8 __attribute__((ext_vector_type(8)));
typedef float f32x4 __attribute__((ext_vector_type(4)));
typedef unsigned int uint32x4 __attribute__((ext_vector_type(4)));
typedef unsigned int uint32x2 __attribute__((ext_vector_type(2)));

__device__ __forceinline__ float atanh_ref(float x) {
  x = fminf(x, 1.0f - EPSF);
  return 0.5f * (log1pf(x + EPSF) - log1pf(EPSF - x));
}

__device__ __forceinline__ unsigned short f2bf(float x) {
  unsigned int u = __float_as_uint(x);
  unsigned int r = (u + 0x7fffu + ((u >> 16) & 1u)) >> 16;
  return (unsigned short)r;
}
__device__ __forceinline__ float bf2f(unsigned short h) {
  return __uint_as_float(((unsigned int)h) << 16);
}

__device__ __forceinline__ void gload16(const void* g, void* l) {
  __builtin_amdgcn_global_load_lds(
      (const __attribute__((address_space(1))) unsigned int*)g,
      (__attribute__((address_space(3))) unsigned int*)l, 16, 0, 0);
}

// ---- explicit MALL write-through / read-through accessors (sc0+sc1) ------
// EARLY-CLOBBER output: dest must not alias the 64b address pair.
__device__ __forceinline__ uint32x4 ldg_sc16(const void* p) {
  uint32x4 r;
  asm volatile("global_load_dwordx4 %0, %1, off sc0 sc1" : "=&v"(r) : "v"(p));
  return r;
}
__device__ __forceinline__ void stg_sc4(void* p, unsigned v) {
  asm volatile("global_store_dword %0, %1, off sc0 sc1" :: "v"(p), "v"(v) : "memory");
}
__device__ __forceinline__ void stg_sc8(void* p, uint32x2 v) {
  asm volatile("global_store_dwordx2 %0, %1, off sc0 sc1" :: "v"(p), "v"(v) : "memory");
}
// Drain ALL outstanding VMEM of this wave. RULE #18: any consumer of
// inline-asm load results must sit behind a sched_barrier(0) AFTER this.
__device__ __forceinline__ void drain_vmem() {
  asm volatile("s_waitcnt vmcnt(0)" ::: "memory");
}

// reduce two values across a 256-thread block; result broadcast to all threads
__device__ __forceinline__ void block_reduce2(float& v0, float& v1, float* lds) {
  #pragma unroll
  for (int off = 32; off > 0; off >>= 1) {
    v0 += __shfl_down(v0, off, 64);
    v1 += __shfl_down(v1, off, 64);
  }
  const int lane = threadIdx.x & 63;
  const int wid  = threadIdx.x >> 6;
  if (lane == 0) { lds[wid * 2] = v0; lds[wid * 2 + 1] = v1; }
  __syncthreads();
  if (threadIdx.x == 0) {
    float s0 = 0.f, s1 = 0.f;
    #pragma unroll
    for (int w = 0; w < 4; ++w) { s0 += lds[w * 2]; s1 += lds[w * 2 + 1]; }
    lds[0] = s0; lds[1] = s1;
  }
  __syncthreads();
  v0 = lds[0]; v1 = lds[1];
  __syncthreads();
}

// ---------------------------------------------------------------------------
// Fence-free 64-block barrier (per rq quarter; quarters never exchange data).
// drain_vmem() BEFORE syncthreads (asm sc-stores invisible to compiler
// waitcnt pass), flag sc-store, sc-poll with fused waitcnt.
// ---------------------------------------------------------------------------
__device__ __forceinline__ void gbar3(unsigned* __restrict__ flags, int rq,
                                      int ci, unsigned target) {
  drain_vmem();
  __syncthreads();
  if (threadIdx.x == 0)
    stg_sc4(flags + rq * 64 + ci, target);
  if (threadIdx.x < 64) {
    const unsigned* p0 = flags + rq * 64 + threadIdx.x;
    for (;;) {
      unsigned f0;
      asm volatile("global_load_dword %0, %1, off sc0 sc1\n\t"
                   "s_waitcnt vmcnt(0)"
                   : "=&v"(f0) : "v"(p0) : "memory");
      if (__all(f0 >= target)) break;
      __builtin_amdgcn_s_sleep(1);
    }
  }
  __syncthreads();
}

// ---------------------------------------------------------------------------
// Convert inputs to bf16 hi/lo planes, permuting rows (b*256+t) -> (t*64+b).
// ---------------------------------------------------------------------------
__global__ __launch_bounds__(256) void convert_a(const float* __restrict__ inp,
                                                 unsigned short* __restrict__ Ah,
                                                 unsigned short* __restrict__ Al) {
  const int i = blockIdx.x;
  const int r = ((i & 255) << 6) + (i >> 8);
  const float* src = inp + (size_t)i * KDIM;
  unsigned short* dh = Ah + (size_t)r * KDIM;
  unsigned short* dl = Al + (size_t)r * KDIM;
  const int base = threadIdx.x * 8;
  float4 v0 = *(const float4*)(src + base);
  float4 v1 = *(const float4*)(src + base + 4);
  float f[8] = {v0.x, v0.y, v0.z, v0.w, v1.x, v1.y, v1.z, v1.w};
  unsigned short h[8], l[8];
  #pragma unroll
  for (int j = 0; j < 8; ++j) {
    unsigned short hb = f2bf(f[j]);
    h[j] = hb;
    l[j] = f2bf(f[j] - bf2f(hb));
  }
  *(bf16x8*)(dh + base) = *(bf16x8*)h;
  *(bf16x8*)(dl + base) = *(bf16x8*)l;
}

// ---------------------------------------------------------------------------
// Transpose + convert M (2048x2048) into M^T bf16 hi/lo: Bt[n][k] = M[k][n].
// ---------------------------------------------------------------------------
__global__ __launch_bounds__(256) void convert_bt(const float* __restrict__ M,
                                                  unsigned short* __restrict__ Bh,
                                                  unsigned short* __restrict__ Bl) {
  __shared__ float t[64][65];
  const int k0 = blockIdx.y * 64, nn0 = blockIdx.x * 64;
  const int tid = threadIdx.x;
  #pragma unroll
  for (int j = 0; j < 4; ++j) {
    int idx = tid + j * 256;
    int r = idx >> 4, c4 = (idx & 15) * 4;
    float4 v = *(const float4*)(M + (size_t)(k0 + r) * KDIM + nn0 + c4);
    t[r][c4 + 0] = v.x; t[r][c4 + 1] = v.y; t[r][c4 + 2] = v.z; t[r][c4 + 3] = v.w;
  }
  __syncthreads();
  #pragma unroll
  for (int j = 0; j < 4; ++j) {
    int idx = tid + j * 256;
    int n = idx >> 4, ks = (idx & 15) * 4;
    unsigned short hh[4], ll[4];
    #pragma unroll
    for (int q = 0; q < 4; ++q) {
      float x = t[ks + q][n];
      unsigned short hb = f2bf(x);
      hh[q] = hb;
      ll[q] = f2bf(x - bf2f(hb));
    }
    *(ushort4*)(Bh + (size_t)(nn0 + n) * KDIM + k0 + ks) = *(ushort4*)hh;
    *(ushort4*)(Bl + (size_t)(nn0 + n) * KDIM + k0 + ks) = *(ushort4*)ll;
  }
}

// ---------------------------------------------------------------------------
// bf16x3-split MFMA GEMM for Ux.
// ---------------------------------------------------------------------------
__global__ __launch_bounds__(256) void gemm_mfma3(const unsigned short* __restrict__ Ah,
                                                  const unsigned short* __restrict__ Al,
                                                  const unsigned short* __restrict__ Bh,
                                                  const unsigned short* __restrict__ Bl,
                                                  float* __restrict__ C) {
  __shared__ unsigned char LAh[8192], LAl[8192], LBh[8192], LBl[8192];
  const int tid = threadIdx.x;
  const int lane = tid & 63;
  const int w = tid >> 6;
  const int wr = w >> 1, wc = w & 1;
  const int m0 = blockIdx.x * 128;
  const int n0 = blockIdx.y * 128;

  f32x4 acc[4][4] = {};

  for (int k0 = 0; k0 < KDIM; k0 += 32) {
    #pragma unroll
    for (int j = 0; j < 2; ++j) {
      int c = j * 256 + tid;
      int row = c >> 2;
      int sp = (c & 3) ^ (row & 3);
      size_t aoff = (size_t)(m0 + row) * KDIM + k0 + sp * 8;
      size_t boff = (size_t)(n0 + row) * KDIM + k0 + sp * 8;
      int ldsb = (j * 256 + w * 64) * 16;
      gload16(Ah + aoff, LAh + ldsb);
      gload16(Al + aoff, LAl + ldsb);
      gload16(Bh + boff, LBh + ldsb);
      gload16(Bl + boff, LBl + ldsb);
    }
    __syncthreads();
    bf16x8 ah[4], al[4], bh[4], bl[4];
    #pragma unroll
    for (int i = 0; i < 4; ++i) {
      int arow = wr * 64 + i * 16 + (lane & 15);
      int abyte = arow * 64 + (((lane >> 4) ^ (arow & 3)) * 16);
      ah[i] = *(const bf16x8*)(LAh + abyte);
      al[i] = *(const bf16x8*)(LAl + abyte);
      int brow = wc * 64 + i * 16 + (lane & 15);
      int bbyte = brow * 64 + (((lane >> 4) ^ (brow & 3)) * 16);
      bh[i] = *(const bf16x8*)(LBh + bbyte);
      bl[i] = *(const bf16x8*)(LBl + bbyte);
    }
    #pragma unroll
    for (int i = 0; i < 4; ++i)
      #pragma unroll
      for (int jn = 0; jn < 4; ++jn) {
        acc[i][jn] = __builtin_amdgcn_mfma_f32_16x16x32_bf16(ah[i], bh[jn], acc[i][jn], 0, 0, 0);
        acc[i][jn] = __builtin_amdgcn_mfma_f32_16x16x32_bf16(ah[i], bl[jn], acc[i][jn], 0, 0, 0);
        acc[i][jn] = __builtin_amdgcn_mfma_f32_16x16x32_bf16(al[i], bh[jn], acc[i][jn], 0, 0, 0);
      }
    __syncthreads();
  }
  #pragma unroll
  for (int i = 0; i < 4; ++i) {
    int grow = m0 + wr * 64 + i * 16 + ((lane >> 4) << 2);
    #pragma unroll
    for (int jn = 0; jn < 4; ++jn) {
      int gcol = n0 + wc * 64 + jn * 16 + (lane & 15);
      #pragma unroll
      for (int r = 0; r < 4; ++r)
        C[(size_t)(grow + r) * KDIM + gcol] = acc[i][jn][r];
    }
  }
}

// ---------------------------------------------------------------------------
// Mobius epilogue for the big GEMM (in-place on Mx -> Ux). One block per row.
// ---------------------------------------------------------------------------
__global__ __launch_bounds__(256) void ux_epilogue(const float* __restrict__ inp,
                                                   float* __restrict__ Mx) {
  const int r = blockIdx.x;
  const int t = r >> 6, b = r & 63;
  const float* xrow = inp + ((size_t)(b * T_DIM + t)) * KDIM;
  float* mrow = Mx + (size_t)r * KDIM;
  const int tid = threadIdx.x;
  __shared__ float lds[8];
  float xs2 = 0.f, ms2 = 0.f;
  float m[8];
  #pragma unroll
  for (int j = 0; j < 8; ++j) {
    const int col = tid + j * 256;
    float xv = xrow[col] + EPSF;
    xs2 += xv * xv;
    float mv = mrow[col];
    m[j] = mv;
    ms2 += mv * mv;
  }
  block_reduce2(xs2, ms2, lds);
  float xn = sqrtf(xs2);
  float mnr = sqrtf(ms2);
  float mxn = mnr + EPSF;
  float s = tanhf((mxn / xn) * atanh_ref(xn)) / mxn;
  float na = s * mnr;
  float pf = fminf(1.0f, MAXN / fmaxf(na, EPSF));
  float sc = s * pf;
  #pragma unroll
  for (int j = 0; j < 8; ++j)
    mrow[tid + j * 256] = m[j] * sc;
}

// ---------------------------------------------------------------------------
// Scan init (runs AFTER gemm/epilogue — hx aliases the then-dead Ah/Al).
// hx slot 0 = initial h (0+EPS) bf16 hi/lo; pd[par0][hn2][b][cs] = 32*EPS^2;
// flags zeroed (4 domains x 64). Normal stores — dispatch-boundary writeback
// makes them MALL-visible for scan_coop (protocol proven in r7).
// pd layout: pd[par][v 0..5][b 0..63][cs 0..63], v5 = hn2.
// ---------------------------------------------------------------------------
__global__ __launch_bounds__(256) void scan_init(unsigned short* __restrict__ hx,
                                                 float* __restrict__ pd,
                                                 const float* __restrict__ bvec,
                                                 float* __restrict__ bvbvp,
                                                 unsigned* __restrict__ flags) {
  const int bx = blockIdx.x;  // 64 blocks, one per batch row
  const int tid = threadIdx.x;
  const unsigned short he = f2bf(EPSF);
  const unsigned short le = f2bf(EPSF - bf2f(he));
  unsigned short hv[8], lv[8];
  #pragma unroll
  for (int j = 0; j < 8; ++j) { hv[j] = he; lv[j] = le; }
  const int base = bx * KDIM + tid * 8;
  *(bf16x8*)(hx + base) = *(bf16x8*)hv;
  *(bf16x8*)(hx + 131072 + base) = *(bf16x8*)lv;
  if (bx == 0) {
    // par0 hn2 plane: 64 b x 64 cs entries, each = 32 * EPS^2
    for (int i = tid; i < 4096; i += 256)
      pd[(5 * 64) * 64 + i] = 32.0f * EPSF * EPSF;
    if (tid < NBLK) flags[tid] = 0u;  // 4 domains x 64
  }
  if (bx == 1) {
    __shared__ float lds[8];
    float s = 0.f;
    #pragma unroll
    for (int j = 0; j < 8; ++j) {
      float v = bvec[tid + j * 256] + EPSF;
      s += v * v;
    }
    float dummy = 0.f;
    block_reduce2(s, dummy, lds);
    if (tid == 0) *bvbvp = s;
  }
}

// ---------------------------------------------------------------------------
// Persistent whole-scan kernel. 256 blocks x 1024 threads (16 waves ->
// 4/SIMD, all 256 CUs). Block = 16 rows (rq) x 32 cols (cs); wave-split-K
// = 128. FULL bf16x3 W-GEMM (hh*Wh + hl*Wh + hh*Wl — r13 numerics; the
// r14 W-lo drop failed absmax 4.2e-3 > 2.5e-3). Element phases guarded to
// waves 0..7 (wave-aligned; shuffles safe). Protocol = r13.
// ---------------------------------------------------------------------------
__global__ __launch_bounds__(1024) void scan_coop(const unsigned short* __restrict__ Wth,
                                                  const unsigned short* __restrict__ Wtl,
                                                  unsigned short* __restrict__ hx,
                                                  const float* __restrict__ Ux,
                                                  const float* __restrict__ bvec,
                                                  float* __restrict__ pd,
                                                  const float* __restrict__ bvbvp,
                                                  unsigned* __restrict__ flags,
                                                  float* __restrict__ out) {
  const int tid = threadIdx.x;
  const int bx = blockIdx.x;
  const int lane = tid & 63;
  const int w = tid >> 6;                 // wave 0..15
  // bits[2:0]=xcd, bits[4:3]=rq, bits[7:5]=s -> cs = xcd*8+s (XCD-grouped)
  const int xcd = bx & 7;
  const int rq = (bx >> 3) & 3;           // row quarter (16 rows)
  const int s = bx >> 5;                  // 0..7
  const int cs = xcd * 8 + s;             // 0..63 col slice (32 cols)
  const int ci = cs;                      // flag slot within rq domain
  const int gc0 = cs * 32;
  const int r = tid >> 5;                 // row 0..15 (valid for tid<512)
  const int b = rq * 16 + r;              // batch row
  const int c = tid & 31;                 // col within slice
  const int gc = gc0 + c;

  __shared__ float wtmp[16][16][32];
  __shared__ float MhL[16][32];
  __shared__ float red[16][6];
  __shared__ float cf[16][3];

  const float bvbv = *bvbvp;
  const float bv = (tid < 512) ? (bvec[gc] + EPSF) : 0.f;

  const int arow = (rq * 16 + (lane & 15)) * KDIM;
  const int brow0 = (gc0 + (lane & 15)) * KDIM;
  const int brow1 = (gc0 + 16 + (lane & 15)) * KDIM;
  const int ksub = w * 128 + (lane >> 4) * 8;

  for (int t = 0; t < T_DIM; ++t) {
    const int par = t & 1;
    // ---- phase A: Mh tile (16x32); full bf16x3; hx[t] cached ----
    const unsigned short* hxs = hx + (size_t)(t & 255) * HSLOT;
    f32x4 acc0 = {}, acc1 = {};
    #pragma unroll
    for (int q = 0; q < 4; ++q) {
      const int kq = ksub + q * 32;
      bf16x8 ahv = *(const bf16x8*)(hxs + arow + kq);
      bf16x8 alv = *(const bf16x8*)(hxs + 131072 + arow + kq);
      bf16x8 b0h = *(const bf16x8*)(Wth + brow0 + kq);
      bf16x8 b0l = *(const bf16x8*)(Wtl + brow0 + kq);
      bf16x8 b1h = *(const bf16x8*)(Wth + brow1 + kq);
      bf16x8 b1l = *(const bf16x8*)(Wtl + brow1 + kq);
      acc0 = __builtin_amdgcn_mfma_f32_16x16x32_bf16(ahv, b0h, acc0, 0, 0, 0);
      acc0 = __builtin_amdgcn_mfma_f32_16x16x32_bf16(ahv, b0l, acc0, 0, 0, 0);
      acc0 = __builtin_amdgcn_mfma_f32_16x16x32_bf16(alv, b0h, acc0, 0, 0, 0);
      acc1 = __builtin_amdgcn_mfma_f32_16x16x32_bf16(ahv, b1h, acc1, 0, 0, 0);
      acc1 = __builtin_amdgcn_mfma_f32_16x16x32_bf16(ahv, b1l, acc1, 0, 0, 0);
      acc1 = __builtin_amdgcn_mfma_f32_16x16x32_bf16(alv, b1h, acc1, 0, 0, 0);
    }
    #pragma unroll
    for (int q = 0; q < 4; ++q) {
      const int rr = (lane >> 4) * 4 + q;
      const int cc = lane & 15;
      wtmp[w][rr][cc]      = acc0[q];
      wtmp[w][rr][16 + cc] = acc1[q];
    }
    __syncthreads();
    if (tid < 512) {
      const int rr = tid >> 5, cc = tid & 31;
      float sum = 0.f;
      #pragma unroll
      for (int ww = 0; ww < 16; ++ww) sum += wtmp[ww][rr][cc];
      MhL[rr][cc] = sum;
    }
    __syncthreads();
    float mh = 0.f, uxv = 0.f;
    if (tid < 512) {
      mh = MhL[r][c];
      uxv = __builtin_nontemporal_load(Ux + ((size_t)t * 64 + b) * KDIM + gc) + EPSF;
      float dt0 = mh * mh, dt1 = mh * uxv, dt2 = uxv * uxv;
      float dt3 = mh * bv, dt4 = uxv * bv;
      #pragma unroll
      for (int off = 16; off > 0; off >>= 1) {
        dt0 += __shfl_down(dt0, off, 32);
        dt1 += __shfl_down(dt1, off, 32);
        dt2 += __shfl_down(dt2, off, 32);
        dt3 += __shfl_down(dt3, off, 32);
        dt4 += __shfl_down(dt4, off, 32);
      }
      float* pdp = pd + (size_t)par * 6 * 64 * 64;
      if (c == 0) {
        float dts[5] = {dt0, dt1, dt2, dt3, dt4};
        #pragma unroll
        for (int v = 0; v < 5; ++v)
          stg_sc4(pdp + ((size_t)v * 64 + b) * 64 + cs, __float_as_uint(dts[v]));
      }
    }
    gbar3(flags, rq, ci, (unsigned)(2 * t + 1));

    // ---- phase B: gather dot partials (sc-loads), reduce, scalar chain ----
    float* pdp = pd + (size_t)par * 6 * 64 * 64;
    if (tid < 96) {
      int v = tid >> 4, rr = tid & 15;
      const float* src = pdp + ((size_t)v * 64 + rq * 16 + rr) * 64;
      uint32x4 xs[16];
      #pragma unroll
      for (int q = 0; q < 16; ++q) xs[q] = ldg_sc16(src + q * 4);
      drain_vmem();
      __builtin_amdgcn_sched_barrier(0);  // rule #18
      float sum = 0.f;
      #pragma unroll
      for (int q = 0; q < 16; ++q) {
        sum += __uint_as_float(xs[q][0]) + __uint_as_float(xs[q][1]) +
               __uint_as_float(xs[q][2]) + __uint_as_float(xs[q][3]);
      }
      red[rr][v] = sum;
    }
    __syncthreads();
    if (tid < 16) {
      const float mn2 = red[tid][0], Mhux = red[tid][1], uxux = red[tid][2];
      const float Mhbv = red[tid][3], uxbv = red[tid][4], hn2 = red[tid][5];
      const float hn = sqrtf(hn2);
      const float mnr = sqrtf(mn2);
      const float mxn = mnr + EPSF;
      const float sv = tanhf((mxn / hn) * atanh_ref(hn)) / mxn;
      const float n_a = sv * mnr;
      const float pfa = fminf(1.0f, MAXN / fmaxf(n_a, EPSF));
      const float sa = sv * pfa;
      const float duv = 2.0f * sa * Mhux;
      const float nv = uxux;
      const float na = sa * sa * mn2;
      const float denom = 1.0f + duv + na * nv;
      const float c1 = (1.0f + duv + nv) / denom;
      const float c2 = (1.0f - na) / denom;
      const float r1n2 = c1 * c1 * na + 2.0f * c1 * c2 * sa * Mhux + c2 * c2 * uxux;
      const float pf1 = fminf(1.0f, MAXN / fmaxf(sqrtf(r1n2), EPSF));
      const float Sr1bv = c1 * sa * Mhbv + c2 * uxbv;
      const float duv2 = 2.0f * pf1 * Sr1bv;
      const float na2 = pf1 * pf1 * r1n2;
      const float denom2 = 1.0f + duv2 + na2 * bvbv;
      const float d1 = (1.0f + duv2 + bvbv) / denom2;
      const float d2 = (1.0f - na2) / denom2;
      const float r2n2 = d1 * d1 * na2 + 2.0f * d1 * d2 * pf1 * Sr1bv + d2 * d2 * bvbv;
      const float pf2 = fminf(1.0f, MAXN / fmaxf(sqrtf(r2n2), EPSF));
      cf[tid][0] = pf2 * d1 * pf1 * c1 * sa;  // K_mh
      cf[tid][1] = pf2 * d1 * pf1 * c2;       // K_ux
      cf[tid][2] = pf2 * d2;                  // K_bv
    }
    __syncthreads();
    if (tid < 512) {
      const float Km = cf[r][0], Ku = cf[r][1], Kb = cf[r][2];
      const float hval = Km * mh + Ku * uxv + Kb * bv;
      __builtin_nontemporal_store(hval, out + ((size_t)b * T_DIM + t) * KDIM + gc);
      const float hp = hval + EPSF;
      const unsigned short e0 = f2bf(hp);
      const unsigned short l0 = f2bf(hp - bf2f(e0));
      // pack col pairs via shuffle; even lanes issue dword write-throughs
      unsigned eu = (unsigned)e0, lu = (unsigned)l0;
      unsigned en = __shfl_down(eu, 1, 32);
      unsigned ln = __shfl_down(lu, 1, 32);
      unsigned short* hxn = hx + (size_t)((t + 1) & 255) * HSLOT;
      if ((c & 1) == 0) {
        stg_sc4(hxn + b * KDIM + gc, eu | (en << 16));
        stg_sc4(hxn + 131072 + b * KDIM + gc, lu | (ln << 16));
      }
      float hn2p = hp * hp;
      #pragma unroll
      for (int off = 16; off > 0; off >>= 1) hn2p += __shfl_down(hn2p, off, 32);
      if (c == 0)
        stg_sc4(pd + (size_t)(par ^ 1) * 6 * 64 * 64 + ((size_t)5 * 64 + b) * 64 + cs,
                __float_as_uint(hn2p));
    }
    gbar3(flags, rq, ci, (unsigned)(2 * t + 2));
  }
}

// ---------------------------------------------------------------------------
// Fallback kernels (small-workspace paths).
// ---------------------------------------------------------------------------
__global__ __launch_bounds__(256) void gemm64_splitk(const float* __restrict__ A,
                                                     size_t arstride,
                                                     const float* __restrict__ Bm,
                                                     float* __restrict__ part) {
  const int n0 = blockIdx.x * 64;
  const int kz = blockIdx.y;
  const int kbeg = kz * 256;
  __shared__ float As[16][68];
  __shared__ float Bs[16][64];
  const int tid = threadIdx.x;
  const int tx = tid & 15, ty = tid >> 4;
  const int ai = tid >> 2, ak = (tid & 3) * 4;
  const int bk = tid >> 4, bn = (tid & 15) * 4;
  const float* Arow = A + (size_t)ai * arstride;
  float acc[4][4] = {};
  for (int kt = 0; kt < 16; ++kt) {
    const int k0 = kbeg + kt * 16;
    float4 av = *(const float4*)(Arow + k0 + ak);
    As[ak + 0][ai] = av.x + EPSF;
    As[ak + 1][ai] = av.y + EPSF;
    As[ak + 2][ai] = av.z + EPSF;
    As[ak + 3][ai] = av.w + EPSF;
    float4 bv = *(const float4*)(Bm + (size_t)(k0 + bk) * KDIM + n0 + bn);
    *(float4*)&Bs[bk][bn] = bv;
    __syncthreads();
    #pragma unroll
    for (int k = 0; k < 16; ++k) {
      float4 a4 = *(const float4*)&As[k][ty * 4];
      float4 b4 = *(const float4*)&Bs[k][tx * 4];
      float a[4] = {a4.x, a4.y, a4.z, a4.w};
      float bb[4] = {b4.x, b4.y, b4.z, b4.w};
      #pragma unroll
      for (int i = 0; i < 4; ++i)
        #pragma unroll
        for (int j = 0; j < 4; ++j)
          acc[i][j] = fmaf(a[i], bb[j], acc[i][j]);
    }
    __syncthreads();
  }
  #pragma unroll
  for (int i = 0; i < 4; ++i) {
    float4 o = make_float4(acc[i][0], acc[i][1], acc[i][2], acc[i][3]);
    *(float4*)(part + ((size_t)kz * 64 + ty * 4 + i) * KDIM + n0 + tx * 4) = o;
  }
}

__global__ __launch_bounds__(256) void mob_from_parts(const float* __restrict__ part,
                                                      const float* __restrict__ xbase,
                                                      size_t xstride,
                                                      float* __restrict__ outrows) {
  const int b = blockIdx.x;
  const int tid = threadIdx.x;
  __shared__ float lds[8];
  const float* xrow = xbase + (size_t)b * xstride;
  float xs2 = 0.f, ms2 = 0.f;
  float m[8];
  #pragma unroll
  for (int j = 0; j < 8; ++j) {
    const int col = tid + j * 256;
    float xv = xrow[col] + EPSF;
    xs2 += xv * xv;
    float mv = 0.f;
    for (int kz = 0; kz < 8; ++kz)
      mv += part[((size_t)kz * 64 + b) * KDIM + col];
    m[j] = mv;
    ms2 += mv * mv;
  }
  block_reduce2(xs2, ms2, lds);
  float xn = sqrtf(xs2);
  float mnr = sqrtf(ms2);
  float mxn = mnr + EPSF;
  float s = tanhf((mxn / xn) * atanh_ref(xn)) / mxn;
  float na = s * mnr;
  float pf = fminf(1.0f, MAXN / fmaxf(na, EPSF));
  float sc = s * pf;
  #pragma unroll
  for (int j = 0; j < 8; ++j)
    outrows[(size_t)b * KDIM + tid + j * 256] = m[j] * sc;
}

__global__ __launch_bounds__(256) void step_mobius(const float* __restrict__ part,
                                                   float* __restrict__ h,
                                                   const float* __restrict__ uxrows,
                                                   const float* __restrict__ bvec,
                                                   float* __restrict__ out,
                                                   int t) {
  const int b = blockIdx.x;
  const int tid = threadIdx.x;
  __shared__ float lds[8];
  float mh[8], uxv[8], bv[8];
  float hn2 = 0.f, mn2 = 0.f;
  #pragma unroll
  for (int j = 0; j < 8; ++j) {
    const int col = tid + j * 256;
    float x = h[(size_t)b * KDIM + col] + EPSF;
    hn2 += x * x;
    float m = 0.f;
    for (int kz = 0; kz < 8; ++kz)
      m += part[((size_t)kz * 64 + b) * KDIM + col];
    mh[j] = m;
    mn2 += m * m;
    uxv[j] = uxrows[(size_t)b * KDIM + col] + EPSF;
    bv[j] = bvec[col] + EPSF;
  }
  block_reduce2(hn2, mn2, lds);
  float hn = sqrtf(hn2);
  float mnr = sqrtf(mn2);
  float mxn = mnr + EPSF;
  float s = tanhf((mxn / hn) * atanh_ref(hn)) / mxn;
  float n_a = s * mnr;
  float pfa = fminf(1.0f, MAXN / fmaxf(n_a, EPSF));
  float sa = s * pfa;
  float a[8];
  float duv = 0.f, nv = 0.f;
  #pragma unroll
  for (int j = 0; j < 8; ++j) {
    a[j] = sa * mh[j];
    duv += a[j] * uxv[j];
    nv += uxv[j] * uxv[j];
  }
  block_reduce2(duv, nv, lds);
  duv *= 2.0f;
  float na = sa * sa * mn2;
  float denom = 1.0f + duv + na * nv;
  float c1 = (1.0f + duv + nv) / denom;
  float c2 = (1.0f - na) / denom;
  float r1[8];
  float r1n2 = 0.f, dummy = 0.f;
  #pragma unroll
  for (int j = 0; j < 8; ++j) {
    r1[j] = c1 * a[j] + c2 * uxv[j];
    r1n2 += r1[j] * r1[j];
  }
  block_reduce2(r1n2, dummy, lds);
  float n1 = sqrtf(r1n2);
  float pf1 = fminf(1.0f, MAXN / fmaxf(n1, EPSF));
  float duv2 = 0.f, nv2 = 0.f;
  #pragma unroll
  for (int j = 0; j < 8; ++j) {
    r1[j] *= pf1;
    duv2 += r1[j] * bv[j];
    nv2 += bv[j] * bv[j];
  }
  block_reduce2(duv2, nv2, lds);
  duv2 *= 2.0f;
  float na2 = pf1 * pf1 * r1n2;
  float denom2 = 1.0f + duv2 + na2 * nv2;
  float d1 = (1.0f + duv2 + nv2) / denom2;
  float d2 = (1.0f - na2) / denom2;
  float r2[8];
  float r2n2 = 0.f;
  dummy = 0.f;
  #pragma unroll
  for (int j = 0; j < 8; ++j) {
    r2[j] = d1 * r1[j] + d2 * bv[j];
    r2n2 += r2[j] * r2[j];
  }
  block_reduce2(r2n2, dummy, lds);
  float n2 = sqrtf(r2n2);
  float pf2 = fminf(1.0f, MAXN / fmaxf(n2, EPSF));
  #pragma unroll
  for (int j = 0; j < 8; ++j) {
    const int col = tid + j * 256;
    float vout = r2[j] * pf2;
    h[(size_t)b * KDIM + col] = vout;
    out[((size_t)b * T_DIM + t) * KDIM + col] = vout;
  }
}

extern "C" void kernel_launch(void* const* d_in, const int* in_sizes, int n_in,
                              void* d_out, int out_size, void* d_ws, size_t ws_size,
                              hipStream_t stream) {
  const float* inp  = (const float*)d_in[0];
  const float* wm   = (const float*)d_in[1];
  const float* um   = (const float*)d_in[2];
  const float* bvec = (const float*)d_in[3];
  float* out = (float*)d_out;
  char* ws = (char*)d_ws;

  const size_t UXB  = (size_t)TBROWS * KDIM * 4;   // 134.2 MB
  const size_t AHL  = (size_t)TBROWS * KDIM * 2;   // 67.1 MB (x2 = hx arena)
  const size_t BTB  = (size_t)KDIM * KDIM * 2;     // 8.4 MB
  const size_t PDB  = (size_t)2 * 6 * 64 * 64 * 4; // 192 KB
  const size_t META = 2048;                        // bvbv + flags (4x64)
  const size_t HFP  = (size_t)B_DIM * KDIM * 4;    // 512 KB
  const size_t PART = (size_t)8 * B_DIM * KDIM * 4; // 4 MB

  size_t off = 0;
  float* Ux = (float*)(ws + off); off += UXB;
  unsigned short* Ah = (unsigned short*)(ws + off);       // hx aliases Ah+Al
  unsigned short* hx = Ah; off += AHL;
  unsigned short* Al = (unsigned short*)(ws + off); off += AHL;
  unsigned short* Bh = (unsigned short*)(ws + off); off += BTB;
  unsigned short* Bl = (unsigned short*)(ws + off); off += BTB;
  unsigned short* Wth = (unsigned short*)(ws + off); off += BTB;
  unsigned short* Wtl = (unsigned short*)(ws + off); off += BTB;
  float* pd = (float*)(ws + off); off += PDB;
  float* bvbvp = (float*)(ws + off);
  unsigned* flagsp = (unsigned*)(ws + off + 128); off += META;
  float* hfp = (float*)(ws + off); off += HFP;
  float* part = (float*)(ws + off); off += PART;
  const size_t NEED_COOP = off;
  const size_t NEED_MFMA = UXB + 2 * AHL + 2 * BTB + HFP + PART;
  const size_t NEED_FP32 = UXB + HFP + PART;

  if (ws_size >= NEED_COOP) {
    convert_a<<<TBROWS, 256, 0, stream>>>(inp, Ah, Al);
    convert_bt<<<dim3(32, 32), 256, 0, stream>>>(um, Bh, Bl);
    convert_bt<<<dim3(32, 32), 256, 0, stream>>>(wm, Wth, Wtl);
    gemm_mfma3<<<dim3(128, 16), 256, 0, stream>>>(Ah, Al, Bh, Bl, Ux);
    ux_epilogue<<<TBROWS, 256, 0, stream>>>(inp, Ux);
    // scan_init AFTER the GEMM: hx slot 0 overwrites (now-dead) Ah rows.
    scan_init<<<B_DIM, 256, 0, stream>>>(hx, pd, bvec, bvbvp, flagsp);
    scan_coop<<<NBLK, 1024, 0, stream>>>(Wth, Wtl, hx, Ux, bvec, pd, bvbvp,
                                         flagsp, out);
  } else if (ws_size >= NEED_MFMA) {
    float* Ux2 = (float*)ws;
    unsigned short* Ah2 = (unsigned short*)(ws + UXB);
    unsigned short* Al2 = (unsigned short*)(ws + UXB + AHL);
    unsigned short* Bh2 = (unsigned short*)(ws + UXB + 2 * AHL);
    unsigned short* Bl2 = (unsigned short*)(ws + UXB + 2 * AHL + BTB);
    float* h2 = (float*)(ws + UXB + 2 * AHL + 2 * BTB);
    float* part2 = (float*)(ws + UXB + 2 * AHL + 2 * BTB + HFP);
    hipMemsetAsync(h2, 0, HFP, stream);
    convert_a<<<TBROWS, 256, 0, stream>>>(inp, Ah2, Al2);
    convert_bt<<<dim3(32, 32), 256, 0, stream>>>(um, Bh2, Bl2);
    gemm_mfma3<<<dim3(128, 16), 256, 0, stream>>>(Ah2, Al2, Bh2, Bl2, Ux2);
    ux_epilogue<<<TBROWS, 256, 0, stream>>>(inp, Ux2);
    for (int t = 0; t < T_DIM; ++t) {
      gemm64_splitk<<<dim3(32, 8), 256, 0, stream>>>(h2, (size_t)KDIM, wm, part2);
      step_mobius<<<B_DIM, 256, 0, stream>>>(part2, h2, Ux2 + (size_t)t * B_DIM * KDIM,
                                             bvec, out, t);
    }
  } else {
    float* h2 = (float*)ws;
    float* part2 = (float*)(ws + HFP);
    float* partU = (float*)(ws + HFP + PART);
    float* uxstep = (float*)(ws + HFP + 2 * PART);
    hipMemsetAsync(h2, 0, HFP, stream);
    for (int t = 0; t < T_DIM; ++t) {
      const float* xt = inp + (size_t)t * KDIM;
      gemm64_splitk<<<dim3(32, 8), 256, 0, stream>>>(xt, (size_t)T_DIM * KDIM, um, partU);
      mob_from_parts<<<B_DIM, 256, 0, stream>>>(partU, xt, (size_t)T_DIM * KDIM, uxstep);
      gemm64_splitk<<<dim3(32, 8), 256, 0, stream>>>(h2, (size_t)KDIM, wm, part2);
      step_mobius<<<B_DIM, 256, 0, stream>>>(part2, h2, uxstep, bvec, out, t);
    }
  }
}

// Round 16
// 3896.924 us; speedup vs baseline: 1.1748x; 1.1748x over previous
//
#include <hip/hip_runtime.h>
#include <math.h>

#define T_DIM 256
#define B_DIM 64
#define KDIM 2048   // I*D == H*D
#define TBROWS 16384
#define NBLK 256      // persistent scan grid: 4 rq x 64 cs
#define HSLOT 262144  // ushorts per hx slot: 2 planes x 64 x 2048
#define WPAD 34       // wtmp row stride (floats): 4-row group offset = 136%32=8 -> 2-way max

constexpr float EPSF = 1e-15f;
constexpr float MAXN = 1.0f - 1e-5f;

typedef short bf16x8 __attribute__((ext_vector_type(8)));
typedef float f32x4 __attribute__((ext_vector_type(4)));
typedef unsigned int uint32x4 __attribute__((ext_vector_type(4)));
typedef unsigned int uint32x2 __attribute__((ext_vector_type(2)));

__device__ __forceinline__ float atanh_ref(float x) {
  x = fminf(x, 1.0f - EPSF);
  return 0.5f * (log1pf(x + EPSF) - log1pf(EPSF - x));
}

__device__ __forceinline__ unsigned short f2bf(float x) {
  unsigned int u = __float_as_uint(x);
  unsigned int r = (u + 0x7fffu + ((u >> 16) & 1u)) >> 16;
  return (unsigned short)r;
}
__device__ __forceinline__ float bf2f(unsigned short h) {
  return __uint_as_float(((unsigned int)h) << 16);
}

__device__ __forceinline__ void gload16(const void* g, void* l) {
  __builtin_amdgcn_global_load_lds(
      (const __attribute__((address_space(1))) unsigned int*)g,
      (__attribute__((address_space(3))) unsigned int*)l, 16, 0, 0);
}

// ---- explicit MALL write-through / read-through accessors (sc0+sc1) ------
// EARLY-CLOBBER output: dest must not alias the 64b address pair.
__device__ __forceinline__ uint32x4 ldg_sc16(const void* p) {
  uint32x4 r;
  asm volatile("global_load_dwordx4 %0, %1, off sc0 sc1" : "=&v"(r) : "v"(p));
  return r;
}
__device__ __forceinline__ void stg_sc4(void* p, unsigned v) {
  asm volatile("global_store_dword %0, %1, off sc0 sc1" :: "v"(p), "v"(v) : "memory");
}
__device__ __forceinline__ void stg_sc8(void* p, uint32x2 v) {
  asm volatile("global_store_dwordx2 %0, %1, off sc0 sc1" :: "v"(p), "v"(v) : "memory");
}
// Drain ALL outstanding VMEM of this wave. RULE #18: any consumer of
// inline-asm load results must sit behind a sched_barrier(0) AFTER this.
__device__ __forceinline__ void drain_vmem() {
  asm volatile("s_waitcnt vmcnt(0)" ::: "memory");
}

// reduce two values across a 256-thread block; result broadcast to all threads
__device__ __forceinline__ void block_reduce2(float& v0, float& v1, float* lds) {
  #pragma unroll
  for (int off = 32; off > 0; off >>= 1) {
    v0 += __shfl_down(v0, off, 64);
    v1 += __shfl_down(v1, off, 64);
  }
  const int lane = threadIdx.x & 63;
  const int wid  = threadIdx.x >> 6;
  if (lane == 0) { lds[wid * 2] = v0; lds[wid * 2 + 1] = v1; }
  __syncthreads();
  if (threadIdx.x == 0) {
    float s0 = 0.f, s1 = 0.f;
    #pragma unroll
    for (int w = 0; w < 4; ++w) { s0 += lds[w * 2]; s1 += lds[w * 2 + 1]; }
    lds[0] = s0; lds[1] = s1;
  }
  __syncthreads();
  v0 = lds[0]; v1 = lds[1];
  __syncthreads();
}

// ---------------------------------------------------------------------------
// Fence-free 64-block barrier (per rq quarter; quarters never exchange data).
// drain_vmem() BEFORE syncthreads (asm sc-stores invisible to compiler
// waitcnt pass), flag sc-store, sc-poll with fused waitcnt.
// ---------------------------------------------------------------------------
__device__ __forceinline__ void gbar3(unsigned* __restrict__ flags, int rq,
                                      int ci, unsigned target) {
  drain_vmem();
  __syncthreads();
  if (threadIdx.x == 0)
    stg_sc4(flags + rq * 64 + ci, target);
  if (threadIdx.x < 64) {
    const unsigned* p0 = flags + rq * 64 + threadIdx.x;
    for (;;) {
      unsigned f0;
      asm volatile("global_load_dword %0, %1, off sc0 sc1\n\t"
                   "s_waitcnt vmcnt(0)"
                   : "=&v"(f0) : "v"(p0) : "memory");
      if (__all(f0 >= target)) break;
      __builtin_amdgcn_s_sleep(1);
    }
  }
  __syncthreads();
}

// ---------------------------------------------------------------------------
// Convert inputs to bf16 hi/lo planes, permuting rows (b*256+t) -> (t*64+b).
// ---------------------------------------------------------------------------
__global__ __launch_bounds__(256) void convert_a(const float* __restrict__ inp,
                                                 unsigned short* __restrict__ Ah,
                                                 unsigned short* __restrict__ Al) {
  const int i = blockIdx.x;
  const int r = ((i & 255) << 6) + (i >> 8);
  const float* src = inp + (size_t)i * KDIM;
  unsigned short* dh = Ah + (size_t)r * KDIM;
  unsigned short* dl = Al + (size_t)r * KDIM;
  const int base = threadIdx.x * 8;
  float4 v0 = *(const float4*)(src + base);
  float4 v1 = *(const float4*)(src + base + 4);
  float f[8] = {v0.x, v0.y, v0.z, v0.w, v1.x, v1.y, v1.z, v1.w};
  unsigned short h[8], l[8];
  #pragma unroll
  for (int j = 0; j < 8; ++j) {
    unsigned short hb = f2bf(f[j]);
    h[j] = hb;
    l[j] = f2bf(f[j] - bf2f(hb));
  }
  *(bf16x8*)(dh + base) = *(bf16x8*)h;
  *(bf16x8*)(dl + base) = *(bf16x8*)l;
}

// ---------------------------------------------------------------------------
// Transpose + convert M (2048x2048) into M^T bf16 hi/lo: Bt[n][k] = M[k][n].
// ---------------------------------------------------------------------------
__global__ __launch_bounds__(256) void convert_bt(const float* __restrict__ M,
                                                  unsigned short* __restrict__ Bh,
                                                  unsigned short* __restrict__ Bl) {
  __shared__ float t[64][65];
  const int k0 = blockIdx.y * 64, nn0 = blockIdx.x * 64;
  const int tid = threadIdx.x;
  #pragma unroll
  for (int j = 0; j < 4; ++j) {
    int idx = tid + j * 256;
    int r = idx >> 4, c4 = (idx & 15) * 4;
    float4 v = *(const float4*)(M + (size_t)(k0 + r) * KDIM + nn0 + c4);
    t[r][c4 + 0] = v.x; t[r][c4 + 1] = v.y; t[r][c4 + 2] = v.z; t[r][c4 + 3] = v.w;
  }
  __syncthreads();
  #pragma unroll
  for (int j = 0; j < 4; ++j) {
    int idx = tid + j * 256;
    int n = idx >> 4, ks = (idx & 15) * 4;
    unsigned short hh[4], ll[4];
    #pragma unroll
    for (int q = 0; q < 4; ++q) {
      float x = t[ks + q][n];
      unsigned short hb = f2bf(x);
      hh[q] = hb;
      ll[q] = f2bf(x - bf2f(hb));
    }
    *(ushort4*)(Bh + (size_t)(nn0 + n) * KDIM + k0 + ks) = *(ushort4*)hh;
    *(ushort4*)(Bl + (size_t)(nn0 + n) * KDIM + k0 + ks) = *(ushort4*)ll;
  }
}

// ---------------------------------------------------------------------------
// bf16x3-split MFMA GEMM for Ux.
// ---------------------------------------------------------------------------
__global__ __launch_bounds__(256) void gemm_mfma3(const unsigned short* __restrict__ Ah,
                                                  const unsigned short* __restrict__ Al,
                                                  const unsigned short* __restrict__ Bh,
                                                  const unsigned short* __restrict__ Bl,
                                                  float* __restrict__ C) {
  __shared__ unsigned char LAh[8192], LAl[8192], LBh[8192], LBl[8192];
  const int tid = threadIdx.x;
  const int lane = tid & 63;
  const int w = tid >> 6;
  const int wr = w >> 1, wc = w & 1;
  const int m0 = blockIdx.x * 128;
  const int n0 = blockIdx.y * 128;

  f32x4 acc[4][4] = {};

  for (int k0 = 0; k0 < KDIM; k0 += 32) {
    #pragma unroll
    for (int j = 0; j < 2; ++j) {
      int c = j * 256 + tid;
      int row = c >> 2;
      int sp = (c & 3) ^ (row & 3);
      size_t aoff = (size_t)(m0 + row) * KDIM + k0 + sp * 8;
      size_t boff = (size_t)(n0 + row) * KDIM + k0 + sp * 8;
      int ldsb = (j * 256 + w * 64) * 16;
      gload16(Ah + aoff, LAh + ldsb);
      gload16(Al + aoff, LAl + ldsb);
      gload16(Bh + boff, LBh + ldsb);
      gload16(Bl + boff, LBl + ldsb);
    }
    __syncthreads();
    bf16x8 ah[4], al[4], bh[4], bl[4];
    #pragma unroll
    for (int i = 0; i < 4; ++i) {
      int arow = wr * 64 + i * 16 + (lane & 15);
      int abyte = arow * 64 + (((lane >> 4) ^ (arow & 3)) * 16);
      ah[i] = *(const bf16x8*)(LAh + abyte);
      al[i] = *(const bf16x8*)(LAl + abyte);
      int brow = wc * 64 + i * 16 + (lane & 15);
      int bbyte = brow * 64 + (((lane >> 4) ^ (brow & 3)) * 16);
      bh[i] = *(const bf16x8*)(LBh + bbyte);
      bl[i] = *(const bf16x8*)(LBl + bbyte);
    }
    #pragma unroll
    for (int i = 0; i < 4; ++i)
      #pragma unroll
      for (int jn = 0; jn < 4; ++jn) {
        acc[i][jn] = __builtin_amdgcn_mfma_f32_16x16x32_bf16(ah[i], bh[jn], acc[i][jn], 0, 0, 0);
        acc[i][jn] = __builtin_amdgcn_mfma_f32_16x16x32_bf16(ah[i], bl[jn], acc[i][jn], 0, 0, 0);
        acc[i][jn] = __builtin_amdgcn_mfma_f32_16x16x32_bf16(al[i], bh[jn], acc[i][jn], 0, 0, 0);
      }
    __syncthreads();
  }
  #pragma unroll
  for (int i = 0; i < 4; ++i) {
    int grow = m0 + wr * 64 + i * 16 + ((lane >> 4) << 2);
    #pragma unroll
    for (int jn = 0; jn < 4; ++jn) {
      int gcol = n0 + wc * 64 + jn * 16 + (lane & 15);
      #pragma unroll
      for (int r = 0; r < 4; ++r)
        C[(size_t)(grow + r) * KDIM + gcol] = acc[i][jn][r];
    }
  }
}

// ---------------------------------------------------------------------------
// Mobius epilogue for the big GEMM (in-place on Mx -> Ux). One block per row.
// ---------------------------------------------------------------------------
__global__ __launch_bounds__(256) void ux_epilogue(const float* __restrict__ inp,
                                                   float* __restrict__ Mx) {
  const int r = blockIdx.x;
  const int t = r >> 6, b = r & 63;
  const float* xrow = inp + ((size_t)(b * T_DIM + t)) * KDIM;
  float* mrow = Mx + (size_t)r * KDIM;
  const int tid = threadIdx.x;
  __shared__ float lds[8];
  float xs2 = 0.f, ms2 = 0.f;
  float m[8];
  #pragma unroll
  for (int j = 0; j < 8; ++j) {
    const int col = tid + j * 256;
    float xv = xrow[col] + EPSF;
    xs2 += xv * xv;
    float mv = mrow[col];
    m[j] = mv;
    ms2 += mv * mv;
  }
  block_reduce2(xs2, ms2, lds);
  float xn = sqrtf(xs2);
  float mnr = sqrtf(ms2);
  float mxn = mnr + EPSF;
  float s = tanhf((mxn / xn) * atanh_ref(xn)) / mxn;
  float na = s * mnr;
  float pf = fminf(1.0f, MAXN / fmaxf(na, EPSF));
  float sc = s * pf;
  #pragma unroll
  for (int j = 0; j < 8; ++j)
    mrow[tid + j * 256] = m[j] * sc;
}

// ---------------------------------------------------------------------------
// Scan init (runs AFTER gemm/epilogue — hx aliases the then-dead Ah/Al).
// hx slot 0 = initial h (0+EPS) bf16 hi/lo; pd[par0][hn2][b][cs] = 32*EPS^2;
// flags zeroed (4 domains x 64). Normal stores — dispatch-boundary writeback
// makes them MALL-visible for scan_coop (protocol proven in r7).
// pd layout: pd[par][v 0..5][b 0..63][cs 0..63], v5 = hn2.
// ---------------------------------------------------------------------------
__global__ __launch_bounds__(256) void scan_init(unsigned short* __restrict__ hx,
                                                 float* __restrict__ pd,
                                                 const float* __restrict__ bvec,
                                                 float* __restrict__ bvbvp,
                                                 unsigned* __restrict__ flags) {
  const int bx = blockIdx.x;  // 64 blocks, one per batch row
  const int tid = threadIdx.x;
  const unsigned short he = f2bf(EPSF);
  const unsigned short le = f2bf(EPSF - bf2f(he));
  unsigned short hv[8], lv[8];
  #pragma unroll
  for (int j = 0; j < 8; ++j) { hv[j] = he; lv[j] = le; }
  const int base = bx * KDIM + tid * 8;
  *(bf16x8*)(hx + base) = *(bf16x8*)hv;
  *(bf16x8*)(hx + 131072 + base) = *(bf16x8*)lv;
  if (bx == 0) {
    // par0 hn2 plane: 64 b x 64 cs entries, each = 32 * EPS^2
    for (int i = tid; i < 4096; i += 256)
      pd[(5 * 64) * 64 + i] = 32.0f * EPSF * EPSF;
    if (tid < NBLK) flags[tid] = 0u;  // 4 domains x 64
  }
  if (bx == 1) {
    __shared__ float lds[8];
    float s = 0.f;
    #pragma unroll
    for (int j = 0; j < 8; ++j) {
      float v = bvec[tid + j * 256] + EPSF;
      s += v * v;
    }
    float dummy = 0.f;
    block_reduce2(s, dummy, lds);
    if (tid == 0) *bvbvp = s;
  }
}

// ---------------------------------------------------------------------------
// Persistent whole-scan kernel. 256 blocks x 512 threads (r13 champion
// config: 8 waves -> 2/SIMD, all 256 CUs). Block = 16 rows (rq) x 32 cols
// (cs); wave-split-K = 256. wtmp rows padded to WPAD=34 floats: the 4
// lane-groups' write offsets land on banks {0,8,16,24}+c -> max 2-way
// (free) instead of r13/r15's 4-way conflicts. Full bf16x3 numerics.
// Protocol = r13 (rotating cached h, sc dot-slots, drain->flag->poll).
// ---------------------------------------------------------------------------
__global__ __launch_bounds__(512) void scan_coop(const unsigned short* __restrict__ Wth,
                                                 const unsigned short* __restrict__ Wtl,
                                                 unsigned short* __restrict__ hx,
                                                 const float* __restrict__ Ux,
                                                 const float* __restrict__ bvec,
                                                 float* __restrict__ pd,
                                                 const float* __restrict__ bvbvp,
                                                 unsigned* __restrict__ flags,
                                                 float* __restrict__ out) {
  const int tid = threadIdx.x;
  const int bx = blockIdx.x;
  const int lane = tid & 63;
  const int w = tid >> 6;                 // wave 0..7
  // bits[2:0]=xcd, bits[4:3]=rq, bits[7:5]=s -> cs = xcd*8+s (XCD-grouped)
  const int xcd = bx & 7;
  const int rq = (bx >> 3) & 3;           // row quarter (16 rows)
  const int s = bx >> 5;                  // 0..7
  const int cs = xcd * 8 + s;             // 0..63 col slice (32 cols)
  const int ci = cs;                      // flag slot within rq domain
  const int gc0 = cs * 32;
  const int r = tid >> 5;                 // row 0..15
  const int b = rq * 16 + r;              // batch row
  const int c = tid & 31;                 // col within slice
  const int gc = gc0 + c;

  __shared__ float wtmp[8][16][WPAD];
  __shared__ float MhL[16][32];
  __shared__ float red[16][6];
  __shared__ float cf[16][3];

  const float bvbv = *bvbvp;
  const float bv = bvec[gc] + EPSF;

  const int arow = (rq * 16 + (lane & 15)) * KDIM;
  const int brow0 = (gc0 + (lane & 15)) * KDIM;
  const int brow1 = (gc0 + 16 + (lane & 15)) * KDIM;
  const int ksub = w * 256 + (lane >> 4) * 8;

  for (int t = 0; t < T_DIM; ++t) {
    const int par = t & 1;
    // ---- phase A: Mh tile (16x32) via full bf16x3 MFMA; hx[t] cached ----
    const unsigned short* hxs = hx + (size_t)(t & 255) * HSLOT;
    f32x4 acc0 = {}, acc1 = {};
    #pragma unroll
    for (int q = 0; q < 8; ++q) {
      const int kq = ksub + q * 32;
      bf16x8 ahv = *(const bf16x8*)(hxs + arow + kq);
      bf16x8 alv = *(const bf16x8*)(hxs + 131072 + arow + kq);
      bf16x8 b0h = *(const bf16x8*)(Wth + brow0 + kq);
      bf16x8 b0l = *(const bf16x8*)(Wtl + brow0 + kq);
      bf16x8 b1h = *(const bf16x8*)(Wth + brow1 + kq);
      bf16x8 b1l = *(const bf16x8*)(Wtl + brow1 + kq);
      acc0 = __builtin_amdgcn_mfma_f32_16x16x32_bf16(ahv, b0h, acc0, 0, 0, 0);
      acc0 = __builtin_amdgcn_mfma_f32_16x16x32_bf16(ahv, b0l, acc0, 0, 0, 0);
      acc0 = __builtin_amdgcn_mfma_f32_16x16x32_bf16(alv, b0h, acc0, 0, 0, 0);
      acc1 = __builtin_amdgcn_mfma_f32_16x16x32_bf16(ahv, b1h, acc1, 0, 0, 0);
      acc1 = __builtin_amdgcn_mfma_f32_16x16x32_bf16(ahv, b1l, acc1, 0, 0, 0);
      acc1 = __builtin_amdgcn_mfma_f32_16x16x32_bf16(alv, b1h, acc1, 0, 0, 0);
    }
    #pragma unroll
    for (int q = 0; q < 4; ++q) {
      const int rr = (lane >> 4) * 4 + q;
      const int cc = lane & 15;
      wtmp[w][rr][cc]      = acc0[q];
      wtmp[w][rr][16 + cc] = acc1[q];
    }
    __syncthreads();
    {
      const int rr = tid >> 5, cc = tid & 31;
      float sum = 0.f;
      #pragma unroll
      for (int ww = 0; ww < 8; ++ww) sum += wtmp[ww][rr][cc];
      MhL[rr][cc] = sum;
    }
    __syncthreads();
    const float mh = MhL[r][c];
    const float uxv = __builtin_nontemporal_load(
                          Ux + ((size_t)t * 64 + b) * KDIM + gc) + EPSF;
    float dt0 = mh * mh, dt1 = mh * uxv, dt2 = uxv * uxv;
    float dt3 = mh * bv, dt4 = uxv * bv;
    #pragma unroll
    for (int off = 16; off > 0; off >>= 1) {
      dt0 += __shfl_down(dt0, off, 32);
      dt1 += __shfl_down(dt1, off, 32);
      dt2 += __shfl_down(dt2, off, 32);
      dt3 += __shfl_down(dt3, off, 32);
      dt4 += __shfl_down(dt4, off, 32);
    }
    float* pdp = pd + (size_t)par * 6 * 64 * 64;
    if (c == 0) {
      float dts[5] = {dt0, dt1, dt2, dt3, dt4};
      #pragma unroll
      for (int v = 0; v < 5; ++v)
        stg_sc4(pdp + ((size_t)v * 64 + b) * 64 + cs, __float_as_uint(dts[v]));
    }
    gbar3(flags, rq, ci, (unsigned)(2 * t + 1));

    // ---- phase B: gather dot partials (sc-loads), reduce, scalar chain ----
    if (tid < 96) {
      int v = tid >> 4, rr = tid & 15;
      const float* src = pdp + ((size_t)v * 64 + rq * 16 + rr) * 64;
      uint32x4 xs[16];
      #pragma unroll
      for (int q = 0; q < 16; ++q) xs[q] = ldg_sc16(src + q * 4);
      drain_vmem();
      __builtin_amdgcn_sched_barrier(0);  // rule #18
      float sum = 0.f;
      #pragma unroll
      for (int q = 0; q < 16; ++q) {
        sum += __uint_as_float(xs[q][0]) + __uint_as_float(xs[q][1]) +
               __uint_as_float(xs[q][2]) + __uint_as_float(xs[q][3]);
      }
      red[rr][v] = sum;
    }
    __syncthreads();
    if (tid < 16) {
      const float mn2 = red[tid][0], Mhux = red[tid][1], uxux = red[tid][2];
      const float Mhbv = red[tid][3], uxbv = red[tid][4], hn2 = red[tid][5];
      const float hn = sqrtf(hn2);
      const float mnr = sqrtf(mn2);
      const float mxn = mnr + EPSF;
      const float sv = tanhf((mxn / hn) * atanh_ref(hn)) / mxn;
      const float n_a = sv * mnr;
      const float pfa = fminf(1.0f, MAXN / fmaxf(n_a, EPSF));
      const float sa = sv * pfa;
      const float duv = 2.0f * sa * Mhux;
      const float nv = uxux;
      const float na = sa * sa * mn2;
      const float denom = 1.0f + duv + na * nv;
      const float c1 = (1.0f + duv + nv) / denom;
      const float c2 = (1.0f - na) / denom;
      const float r1n2 = c1 * c1 * na + 2.0f * c1 * c2 * sa * Mhux + c2 * c2 * uxux;
      const float pf1 = fminf(1.0f, MAXN / fmaxf(sqrtf(r1n2), EPSF));
      const float Sr1bv = c1 * sa * Mhbv + c2 * uxbv;
      const float duv2 = 2.0f * pf1 * Sr1bv;
      const float na2 = pf1 * pf1 * r1n2;
      const float denom2 = 1.0f + duv2 + na2 * bvbv;
      const float d1 = (1.0f + duv2 + bvbv) / denom2;
      const float d2 = (1.0f - na2) / denom2;
      const float r2n2 = d1 * d1 * na2 + 2.0f * d1 * d2 * pf1 * Sr1bv + d2 * d2 * bvbv;
      const float pf2 = fminf(1.0f, MAXN / fmaxf(sqrtf(r2n2), EPSF));
      cf[tid][0] = pf2 * d1 * pf1 * c1 * sa;  // K_mh
      cf[tid][1] = pf2 * d1 * pf1 * c2;       // K_ux
      cf[tid][2] = pf2 * d2;                  // K_bv
    }
    __syncthreads();
    const float Km = cf[r][0], Ku = cf[r][1], Kb = cf[r][2];
    const float hval = Km * mh + Ku * uxv + Kb * bv;
    __builtin_nontemporal_store(hval, out + ((size_t)b * T_DIM + t) * KDIM + gc);
    const float hp = hval + EPSF;
    const unsigned short e0 = f2bf(hp);
    const unsigned short l0 = f2bf(hp - bf2f(e0));
    // pack col pairs via shuffle; even lanes issue dword write-throughs
    unsigned eu = (unsigned)e0, lu = (unsigned)l0;
    unsigned en = __shfl_down(eu, 1, 32);
    unsigned ln = __shfl_down(lu, 1, 32);
    unsigned short* hxn = hx + (size_t)((t + 1) & 255) * HSLOT;
    if ((c & 1) == 0) {
      stg_sc4(hxn + b * KDIM + gc, eu | (en << 16));
      stg_sc4(hxn + 131072 + b * KDIM + gc, lu | (ln << 16));
    }
    float hn2p = hp * hp;
    #pragma unroll
    for (int off = 16; off > 0; off >>= 1) hn2p += __shfl_down(hn2p, off, 32);
    if (c == 0)
      stg_sc4(pd + (size_t)(par ^ 1) * 6 * 64 * 64 + ((size_t)5 * 64 + b) * 64 + cs,
              __float_as_uint(hn2p));
    gbar3(flags, rq, ci, (unsigned)(2 * t + 2));
  }
}

// ---------------------------------------------------------------------------
// Fallback kernels (small-workspace paths).
// ---------------------------------------------------------------------------
__global__ __launch_bounds__(256) void gemm64_splitk(const float* __restrict__ A,
                                                     size_t arstride,
                                                     const float* __restrict__ Bm,
                                                     float* __restrict__ part) {
  const int n0 = blockIdx.x * 64;
  const int kz = blockIdx.y;
  const int kbeg = kz * 256;
  __shared__ float As[16][68];
  __shared__ float Bs[16][64];
  const int tid = threadIdx.x;
  const int tx = tid & 15, ty = tid >> 4;
  const int ai = tid >> 2, ak = (tid & 3) * 4;
  const int bk = tid >> 4, bn = (tid & 15) * 4;
  const float* Arow = A + (size_t)ai * arstride;
  float acc[4][4] = {};
  for (int kt = 0; kt < 16; ++kt) {
    const int k0 = kbeg + kt * 16;
    float4 av = *(const float4*)(Arow + k0 + ak);
    As[ak + 0][ai] = av.x + EPSF;
    As[ak + 1][ai] = av.y + EPSF;
    As[ak + 2][ai] = av.z + EPSF;
    As[ak + 3][ai] = av.w + EPSF;
    float4 bv = *(const float4*)(Bm + (size_t)(k0 + bk) * KDIM + n0 + bn);
    *(float4*)&Bs[bk][bn] = bv;
    __syncthreads();
    #pragma unroll
    for (int k = 0; k < 16; ++k) {
      float4 a4 = *(const float4*)&As[k][ty * 4];
      float4 b4 = *(const float4*)&Bs[k][tx * 4];
      float a[4] = {a4.x, a4.y, a4.z, a4.w};
      float bb[4] = {b4.x, b4.y, b4.z, b4.w};
      #pragma unroll
      for (int i = 0; i < 4; ++i)
        #pragma unroll
        for (int j = 0; j < 4; ++j)
          acc[i][j] = fmaf(a[i], bb[j], acc[i][j]);
    }
    __syncthreads();
  }
  #pragma unroll
  for (int i = 0; i < 4; ++i) {
    float4 o = make_float4(acc[i][0], acc[i][1], acc[i][2], acc[i][3]);
    *(float4*)(part + ((size_t)kz * 64 + ty * 4 + i) * KDIM + n0 + tx * 4) = o;
  }
}

__global__ __launch_bounds__(256) void mob_from_parts(const float* __restrict__ part,
                                                      const float* __restrict__ xbase,
                                                      size_t xstride,
                                                      float* __restrict__ outrows) {
  const int b = blockIdx.x;
  const int tid = threadIdx.x;
  __shared__ float lds[8];
  const float* xrow = xbase + (size_t)b * xstride;
  float xs2 = 0.f, ms2 = 0.f;
  float m[8];
  #pragma unroll
  for (int j = 0; j < 8; ++j) {
    const int col = tid + j * 256;
    float xv = xrow[col] + EPSF;
    xs2 += xv * xv;
    float mv = 0.f;
    for (int kz = 0; kz < 8; ++kz)
      mv += part[((size_t)kz * 64 + b) * KDIM + col];
    m[j] = mv;
    ms2 += mv * mv;
  }
  block_reduce2(xs2, ms2, lds);
  float xn = sqrtf(xs2);
  float mnr = sqrtf(ms2);
  float mxn = mnr + EPSF;
  float s = tanhf((mxn / xn) * atanh_ref(xn)) / mxn;
  float na = s * mnr;
  float pf = fminf(1.0f, MAXN / fmaxf(na, EPSF));
  float sc = s * pf;
  #pragma unroll
  for (int j = 0; j < 8; ++j)
    outrows[(size_t)b * KDIM + tid + j * 256] = m[j] * sc;
}

__global__ __launch_bounds__(256) void step_mobius(const float* __restrict__ part,
                                                   float* __restrict__ h,
                                                   const float* __restrict__ uxrows,
                                                   const float* __restrict__ bvec,
                                                   float* __restrict__ out,
                                                   int t) {
  const int b = blockIdx.x;
  const int tid = threadIdx.x;
  __shared__ float lds[8];
  float mh[8], uxv[8], bv[8];
  float hn2 = 0.f, mn2 = 0.f;
  #pragma unroll
  for (int j = 0; j < 8; ++j) {
    const int col = tid + j * 256;
    float x = h[(size_t)b * KDIM + col] + EPSF;
    hn2 += x * x;
    float m = 0.f;
    for (int kz = 0; kz < 8; ++kz)
      m += part[((size_t)kz * 64 + b) * KDIM + col];
    mh[j] = m;
    mn2 += m * m;
    uxv[j] = uxrows[(size_t)b * KDIM + col] + EPSF;
    bv[j] = bvec[col] + EPSF;
  }
  block_reduce2(hn2, mn2, lds);
  float hn = sqrtf(hn2);
  float mnr = sqrtf(mn2);
  float mxn = mnr + EPSF;
  float s = tanhf((mxn / hn) * atanh_ref(hn)) / mxn;
  float n_a = s * mnr;
  float pfa = fminf(1.0f, MAXN / fmaxf(n_a, EPSF));
  float sa = s * pfa;
  float a[8];
  float duv = 0.f, nv = 0.f;
  #pragma unroll
  for (int j = 0; j < 8; ++j) {
    a[j] = sa * mh[j];
    duv += a[j] * uxv[j];
    nv += uxv[j] * uxv[j];
  }
  block_reduce2(duv, nv, lds);
  duv *= 2.0f;
  float na = sa * sa * mn2;
  float denom = 1.0f + duv + na * nv;
  float c1 = (1.0f + duv + nv) / denom;
  float c2 = (1.0f - na) / denom;
  float r1[8];
  float r1n2 = 0.f, dummy = 0.f;
  #pragma unroll
  for (int j = 0; j < 8; ++j) {
    r1[j] = c1 * a[j] + c2 * uxv[j];
    r1n2 += r1[j] * r1[j];
  }
  block_reduce2(r1n2, dummy, lds);
  float n1 = sqrtf(r1n2);
  float pf1 = fminf(1.0f, MAXN / fmaxf(n1, EPSF));
  float duv2 = 0.f, nv2 = 0.f;
  #pragma unroll
  for (int j = 0; j < 8; ++j) {
    r1[j] *= pf1;
    duv2 += r1[j] * bv[j];
    nv2 += bv[j] * bv[j];
  }
  block_reduce2(duv2, nv2, lds);
  duv2 *= 2.0f;
  float na2 = pf1 * pf1 * r1n2;
  float denom2 = 1.0f + duv2 + na2 * nv2;
  float d1 = (1.0f + duv2 + nv2) / denom2;
  float d2 = (1.0f - na2) / denom2;
  float r2[8];
  float r2n2 = 0.f;
  dummy = 0.f;
  #pragma unroll
  for (int j = 0; j < 8; ++j) {
    r2[j] = d1 * r1[j] + d2 * bv[j];
    r2n2 += r2[j] * r2[j];
  }
  block_reduce2(r2n2, dummy, lds);
  float n2 = sqrtf(r2n2);
  float pf2 = fminf(1.0f, MAXN / fmaxf(n2, EPSF));
  #pragma unroll
  for (int j = 0; j < 8; ++j) {
    const int col = tid + j * 256;
    float vout = r2[j] * pf2;
    h[(size_t)b * KDIM + col] = vout;
    out[((size_t)b * T_DIM + t) * KDIM + col] = vout;
  }
}

extern "C" void kernel_launch(void* const* d_in, const int* in_sizes, int n_in,
                              void* d_out, int out_size, void* d_ws, size_t ws_size,
                              hipStream_t stream) {
  const float* inp  = (const float*)d_in[0];
  const float* wm   = (const float*)d_in[1];
  const float* um   = (const float*)d_in[2];
  const float* bvec = (const float*)d_in[3];
  float* out = (float*)d_out;
  char* ws = (char*)d_ws;

  const size_t UXB  = (size_t)TBROWS * KDIM * 4;   // 134.2 MB
  const size_t AHL  = (size_t)TBROWS * KDIM * 2;   // 67.1 MB (x2 = hx arena)
  const size_t BTB  = (size_t)KDIM * KDIM * 2;     // 8.4 MB
  const size_t PDB  = (size_t)2 * 6 * 64 * 64 * 4; // 192 KB
  const size_t META = 2048;                        // bvbv + flags (4x64)
  const size_t HFP  = (size_t)B_DIM * KDIM * 4;    // 512 KB
  const size_t PART = (size_t)8 * B_DIM * KDIM * 4; // 4 MB

  size_t off = 0;
  float* Ux = (float*)(ws + off); off += UXB;
  unsigned short* Ah = (unsigned short*)(ws + off);       // hx aliases Ah+Al
  unsigned short* hx = Ah; off += AHL;
  unsigned short* Al = (unsigned short*)(ws + off); off += AHL;
  unsigned short* Bh = (unsigned short*)(ws + off); off += BTB;
  unsigned short* Bl = (unsigned short*)(ws + off); off += BTB;
  unsigned short* Wth = (unsigned short*)(ws + off); off += BTB;
  unsigned short* Wtl = (unsigned short*)(ws + off); off += BTB;
  float* pd = (float*)(ws + off); off += PDB;
  float* bvbvp = (float*)(ws + off);
  unsigned* flagsp = (unsigned*)(ws + off + 128); off += META;
  float* hfp = (float*)(ws + off); off += HFP;
  float* part = (float*)(ws + off); off += PART;
  const size_t NEED_COOP = off;
  const size_t NEED_MFMA = UXB + 2 * AHL + 2 * BTB + HFP + PART;
  const size_t NEED_FP32 = UXB + HFP + PART;

  if (ws_size >= NEED_COOP) {
    convert_a<<<TBROWS, 256, 0, stream>>>(inp, Ah, Al);
    convert_bt<<<dim3(32, 32), 256, 0, stream>>>(um, Bh, Bl);
    convert_bt<<<dim3(32, 32), 256, 0, stream>>>(wm, Wth, Wtl);
    gemm_mfma3<<<dim3(128, 16), 256, 0, stream>>>(Ah, Al, Bh, Bl, Ux);
    ux_epilogue<<<TBROWS, 256, 0, stream>>>(inp, Ux);
    // scan_init AFTER the GEMM: hx slot 0 overwrites (now-dead) Ah rows.
    scan_init<<<B_DIM, 256, 0, stream>>>(hx, pd, bvec, bvbvp, flagsp);
    scan_coop<<<NBLK, 512, 0, stream>>>(Wth, Wtl, hx, Ux, bvec, pd, bvbvp,
                                        flagsp, out);
  } else if (ws_size >= NEED_MFMA) {
    float* Ux2 = (float*)ws;
    unsigned short* Ah2 = (unsigned short*)(ws + UXB);
    unsigned short* Al2 = (unsigned short*)(ws + UXB + AHL);
    unsigned short* Bh2 = (unsigned short*)(ws + UXB + 2 * AHL);
    unsigned short* Bl2 = (unsigned short*)(ws + UXB + 2 * AHL + BTB);
    float* h2 = (float*)(ws + UXB + 2 * AHL + 2 * BTB);
    float* part2 = (float*)(ws + UXB + 2 * AHL + 2 * BTB + HFP);
    hipMemsetAsync(h2, 0, HFP, stream);
    convert_a<<<TBROWS, 256, 0, stream>>>(inp, Ah2, Al2);
    convert_bt<<<dim3(32, 32), 256, 0, stream>>>(um, Bh2, Bl2);
    gemm_mfma3<<<dim3(128, 16), 256, 0, stream>>>(Ah2, Al2, Bh2, Bl2, Ux2);
    ux_epilogue<<<TBROWS, 256, 0, stream>>>(inp, Ux2);
    for (int t = 0; t < T_DIM; ++t) {
      gemm64_splitk<<<dim3(32, 8), 256, 0, stream>>>(h2, (size_t)KDIM, wm, part2);
      step_mobius<<<B_DIM, 256, 0, stream>>>(part2, h2, Ux2 + (size_t)t * B_DIM * KDIM,
                                             bvec, out, t);
    }
  } else {
    float* h2 = (float*)ws;
    float* part2 = (float*)(ws + HFP);
    float* partU = (float*)(ws + HFP + PART);
    float* uxstep = (float*)(ws + HFP + 2 * PART);
    hipMemsetAsync(h2, 0, HFP, stream);
    for (int t = 0; t < T_DIM; ++t) {
      const float* xt = inp + (size_t)t * KDIM;
      gemm64_splitk<<<dim3(32, 8), 256, 0, stream>>>(xt, (size_t)T_DIM * KDIM, um, partU);
      mob_from_parts<<<B_DIM, 256, 0, stream>>>(partU, xt, (size_t)T_DIM * KDIM, uxstep);
      gemm64_splitk<<<dim3(32, 8), 256, 0, stream>>>(h2, (size_t)KDIM, wm, part2);
      step_mobius<<<B_DIM, 256, 0, stream>>>(part2, h2, uxstep, bvec, out, t);
    }
  }
}